// Round 18
// baseline (339.953 us; speedup 1.0000x reference)
//
#include <hip/hip_runtime.h>
#include <cstdint>

typedef unsigned short u16;
typedef __attribute__((ext_vector_type(8))) short bf16x8;
typedef __attribute__((ext_vector_type(4))) float f32x4;

#define B_    2
#define S_    2048
#define H_    2048
#define G_    4
#define HD_   128
#define QKVW  3072   // fused QKV row width

// v_exp_f32: D = 2^S0  (exp2 semantics, ISA §3)
#define EXP2F(x) __builtin_amdgcn_exp2f(x)

__device__ __forceinline__ u16 f2bf(float f) {
  union { float f; unsigned u; } v; v.f = f;
  unsigned r = v.u + 0x7fffu + ((v.u >> 16) & 1u);
  return (u16)(r >> 16);
}

__device__ __forceinline__ void async16(void* lds_dst, const void* gsrc) {
  __builtin_amdgcn_global_load_lds(
      (__attribute__((address_space(1))) void*)gsrc,
      (__attribute__((address_space(3))) void*)lds_dst, 16, 0, 0);
}

// ------------- fused prelude: X cast (blocks 0..4095) + weight transpose-casts
// (blocks 4096..14335) in one launch -------------
__global__ __launch_bounds__(256)
void prelude_kernel(const float* __restrict__ X, u16* __restrict__ Xb,
                    const float* __restrict__ Wq, const float* __restrict__ Wk,
                    const float* __restrict__ Wv, const float* __restrict__ Wo,
                    u16* __restrict__ Wqkvt, u16* __restrict__ Wot)
{
  int id = blockIdx.x;
  if (id < 4096) {               // ---- X fp32 -> bf16, 8 elems/thread ----
    int i = id * 256 + threadIdx.x;
    const float4* p = (const float4*)X + (size_t)i * 2;
    float4 a = p[0], b = p[1];
    u16 h[8] = { f2bf(a.x), f2bf(a.y), f2bf(a.z), f2bf(a.w),
                 f2bf(b.x), f2bf(b.y), f2bf(b.z), f2bf(b.w) };
    *(uint4*)(Xb + (size_t)i * 8) = *(const uint4*)h;
    return;
  }
  id -= 4096;                    // ---- weight transpose-cast ----
  const float* W; u16* Wt; int Ndim, bx;
  if (id < 4096)      { W = Wq; Wt = Wqkvt;                        Ndim = 2048; bx = id;        }
  else if (id < 5120) { W = Wk; Wt = Wqkvt + (size_t)2048 * 2048;  Ndim = 512;  bx = id - 4096; }
  else if (id < 6144) { W = Wv; Wt = Wqkvt + (size_t)2560 * 2048;  Ndim = 512;  bx = id - 5120; }
  else                { W = Wo; Wt = Wot;                          Ndim = 2048; bx = id - 6144; }
  const int Kdim = 2048;
  const int nbx = Ndim >> 5;
  const int n0 = (bx % nbx) * 32, k0 = (bx / nbx) * 32;

  __shared__ float t[32][33];
  int tx = threadIdx.x & 31, ty = threadIdx.x >> 5;   // ty 0..7
#pragma unroll
  for (int j = 0; j < 4; ++j)
    t[ty + j * 8][tx] = W[(size_t)(k0 + ty + j * 8) * Ndim + n0 + tx];
  __syncthreads();
#pragma unroll
  for (int j = 0; j < 4; ++j)
    Wt[(size_t)(n0 + ty + j * 8) * Kdim + k0 + tx] = f2bf(t[tx][ty + j * 8]);
}

// ---------------- GEMM: C(M,N) = A(M,K) @ Bt(N,K)^T + bias ----------------
// 8 waves (512 thr), per-wave 64x32 output. R17 XCD row-strip remap.
// MODE 3 writes V columns directly to Vt (B,G,HD,S); Q pre-scaled by
// (1/sqrt(128))*log2(e) so attention uses exp2.
template <int MODE>
__global__ __launch_bounds__(512, 6)
void gemm_bt(const u16* __restrict__ A, const u16* __restrict__ Bt,
             const float* __restrict__ biasQ, const float* __restrict__ biasK,
             const float* __restrict__ biasV, void* __restrict__ Cout,
             u16* __restrict__ VtOut, int Ndim, int Kdim)
{
  __shared__ u16 As[128 * 64];
  __shared__ u16 Bs[128 * 64];
  const int tid  = threadIdx.x;
  const int lane = tid & 63;
  const int wv   = tid >> 6;            // 0..7

  // XCD remap: xcd = wgid&7 owns rows [xcd*4, xcd*4+4) x all cols.
  const int wgid = blockIdx.x + gridDim.x * blockIdx.y;
  const int xcd  = wgid & 7;
  const int idx  = wgid >> 3;
  const int row0 = (xcd * 4 + (idx & 3)) * 128;   // gridDim.x == 32
  const int col0 = (idx >> 2) * 128;

  const int wm = (wv >> 2) * 64;        // 2 row-groups
  const int wn = (wv & 3) * 32;         // 4 col-groups
  const int l15 = lane & 15, l4 = lane >> 4;

  f32x4 acc[4][2] = {};

  for (int kt = 0; kt < Kdim; kt += 64) {
    __syncthreads();
#pragma unroll
    for (int i = 0; i < 2; ++i) {
      int u = i * 512 + tid;
      int r = u >> 3, ci = u & 7;
      async16((char*)As + (i * 512 + wv * 64) * 16,
              A + (size_t)(row0 + r) * Kdim + kt + ci * 8);
    }
#pragma unroll
    for (int i = 0; i < 2; ++i) {
      int u = i * 512 + tid;
      int r = u >> 3, ci = u & 7;
      async16((char*)Bs + (i * 512 + wv * 64) * 16,
              Bt + (size_t)(col0 + r) * Kdim + kt + ci * 8);
    }
    __syncthreads();
#pragma unroll
    for (int ks = 0; ks < 2; ++ks) {
      bf16x8 af[4], bfr[2];
#pragma unroll
      for (int mt = 0; mt < 4; ++mt)
        af[mt] = *(const bf16x8*)&As[(wm + mt * 16 + l15) * 64 + ks * 32 + l4 * 8];
#pragma unroll
      for (int nt = 0; nt < 2; ++nt)
        bfr[nt] = *(const bf16x8*)&Bs[(wn + nt * 16 + l15) * 64 + ks * 32 + l4 * 8];
#pragma unroll
      for (int mt = 0; mt < 4; ++mt)
#pragma unroll
        for (int nt = 0; nt < 2; ++nt)
          acc[mt][nt] = __builtin_amdgcn_mfma_f32_16x16x32_bf16(af[mt], bfr[nt], acc[mt][nt], 0, 0, 0);
    }
  }

#pragma unroll
  for (int mt = 0; mt < 4; ++mt)
#pragma unroll
    for (int nt = 0; nt < 2; ++nt)
#pragma unroll
      for (int r = 0; r < 4; ++r) {
        int rr = row0 + wm + mt * 16 + l4 * 4 + r;
        int cc = col0 + wn + nt * 16 + l15;
        float bias;
        if (MODE == 3)
          bias = cc < 2048 ? biasQ[cc] : (cc < 2560 ? biasK[cc - 2048] : biasV[cc - 2560]);
        else
          bias = biasQ[cc];
        float v = acc[mt][nt][r] + bias;
        if (MODE == 1) {
          ((float*)Cout)[(size_t)rr * Ndim + cc] = v;
        } else {
          if (cc < 2048) v *= 0.12751743383412927f;   // (1/sqrt(128))*log2(e)
          if (cc < 2560) {
            ((u16*)Cout)[(size_t)rr * Ndim + cc] = f2bf(v);
          } else {
            int vc = cc - 2560;                 // 0..511
            int gg = vc >> 7, d = vc & 127;
            VtOut[(((size_t)((rr >> 11) * G_ + gg)) * HD_ + d) * S_ + (rr & 2047)] = f2bf(v);
          }
        }
      }
}

// ---------------- Flash attention (GQA) ----------------
// 8 waves x 32 q-rows (512 thr), KVB=64, direct-Q, exp2 softmax.
// R18: K fragments read DIRECTLY from global (like Q-direct): all 8 waves
// read the same 16KB K-tile -> L1-hot, served by the TA/vector pipe IN
// PARALLEL with LDS serving V+P (the LDS pipe was the measured bottleneck:
// ~350KB/tile/CU vs 620cy MFMA -> MfmaUtil 27%). Removes K LDS reads, K
// staging DMA, and K dbuf: LDS = 16KB(V) + 32KB(P) = 48KB.
// Register safety: 1 block/CU, 8 waves = 2 waves/SIMD -> (512,2) cap is 256
// VGPR; hoisted kf loads (~64 VGPR on top of 112) cost zero occupancy and
// cannot spill (R7's disaster was a 128-cap with 64 live V VGPRs).
__global__ __launch_bounds__(512, 2)
void attn_kernel(const u16* __restrict__ Qb, const u16* __restrict__ Kb,
                 const u16* __restrict__ Vt, u16* __restrict__ Ob)
{
  __shared__ u16 SH[24576];          // 48KB: Vs (16KB) | Ps (32KB)
  u16* Ps = SH + 8192;
  const int tid  = threadIdx.x;
  const int lane = tid & 63, wv = tid >> 6;   // wv 0..7
  const int l15 = lane & 15, l4 = lane >> 4;
  const int qt = blockIdx.x, head = blockIdx.y, b = blockIdx.z;
  const int g = head >> 2;
  const int s0 = qt * 256;

  // --- Q fragments direct from global ---
  bf16x8 qf[2][4];
  {
    const u16* qbase = Qb + ((size_t)(b * S_ + s0 + wv * 32 + l15)) * QKVW + head * HD_ + l4 * 8;
#pragma unroll
    for (int rg = 0; rg < 2; ++rg)
#pragma unroll
      for (int ks = 0; ks < 4; ++ks)
        qf[rg][ks] = *(const bf16x8*)(qbase + (size_t)rg * 16 * QKVW + ks * 32);
  }

  // per-lane K base: row = kt*64 + ct*16 + l15, col = ks*32 + l4*8
  const u16* kbase = Kb + ((size_t)(b * S_) + l15) * QKVW + g * HD_ + l4 * 8;

  float m_r[2][4], lp[2][4];
#pragma unroll
  for (int rg = 0; rg < 2; ++rg)
#pragma unroll
    for (int r = 0; r < 4; ++r) { m_r[rg][r] = 0.f; lp[rg][r] = 0.f; }
  f32x4 aco[2][8] = {};

#define STAGE_V(kt_)                                                           \
  _Pragma("unroll")                                                            \
  for (int i = 0; i < 2; ++i) {                                                \
    int u = i * 512 + tid;                                                     \
    int r = u >> 3;                                                            \
    int ci = (u & 7) ^ (r & 7);                                                \
    async16((char*)SH + (i * 512 + wv * 64) * 16,                              \
            Vt + (((size_t)(b * G_ + g)) * HD_ + r) * S_ + (kt_) * 64 + ci * 8); \
  }

  STAGE_V(0);
  __syncthreads();   // V0 resident

  const u16* Vc = SH;
  for (int kt = 0; kt < S_ / 64; ++kt) {
    // QK^T: kf direct from global (L1-hot across the 8 waves)
    f32x4 sc[2][4] = {};
    const u16* kb = kbase + (size_t)(kt * 64) * QKVW;
    __builtin_amdgcn_s_setprio(1);
#pragma unroll
    for (int ct = 0; ct < 4; ++ct)
#pragma unroll
      for (int ks = 0; ks < 4; ++ks) {
        bf16x8 kf = *(const bf16x8*)(kb + (size_t)(ct * 16) * QKVW + ks * 32);
        sc[0][ct] = __builtin_amdgcn_mfma_f32_16x16x32_bf16(qf[0][ks], kf, sc[0][ct], 0, 0, 0);
        sc[1][ct] = __builtin_amdgcn_mfma_f32_16x16x32_bf16(qf[1][ks], kf, sc[1][ct], 0, 0, 0);
      }
    __builtin_amdgcn_s_setprio(0);

    // per-lane overflow/underflow check (log2 domain; P bounded by 2^8)
    float lm[2][4];
    bool resc = false;
#pragma unroll
    for (int rg = 0; rg < 2; ++rg)
#pragma unroll
      for (int r = 0; r < 4; ++r) {
        lm[rg][r] = fmaxf(fmaxf(sc[rg][0][r], sc[rg][1][r]),
                          fmaxf(sc[rg][2][r], sc[rg][3][r]));
        float d = lm[rg][r] - m_r[rg][r];
        resc |= (d > 8.0f) | (d < -60.0f);
      }
    if (__ballot(resc)) {     // rare: full per-row max update + rescale
#pragma unroll
      for (int rg = 0; rg < 2; ++rg)
#pragma unroll
        for (int r = 0; r < 4; ++r) {
          float mx = lm[rg][r];
          mx = fmaxf(mx, __shfl_xor(mx, 1));
          mx = fmaxf(mx, __shfl_xor(mx, 2));
          mx = fmaxf(mx, __shfl_xor(mx, 4));
          mx = fmaxf(mx, __shfl_xor(mx, 8));
          float mn = fmaxf(m_r[rg][r], mx);
          float al = EXP2F(m_r[rg][r] - mn);
          m_r[rg][r] = mn;
          lp[rg][r] *= al;
#pragma unroll
          for (int dt = 0; dt < 8; ++dt)
            aco[rg][dt][r] *= al;
        }
    }

    // P = exp2(s - m); per-lane partial row-sums; P rows are per-wave-private
#pragma unroll
    for (int rg = 0; rg < 2; ++rg)
#pragma unroll
      for (int ct = 0; ct < 4; ++ct)
#pragma unroll
        for (int r = 0; r < 4; ++r) {
          float p = EXP2F(sc[rg][ct][r] - m_r[rg][r]);
          lp[rg][r] += p;
          int row = wv * 32 + rg * 16 + l4 * 4 + r;
          int col = ct * 16 + l15;
          Ps[row * 64 + (((col >> 3) ^ (row & 7)) << 3) + (col & 7)] = f2bf(p);
        }

    __syncthreads();   // barrier A: V(kt) staging (issued end of prev iter) drained

    // PV: V from LDS (single-buffered; handoff via barriers A/B)
    __builtin_amdgcn_s_setprio(1);
#pragma unroll
    for (int k2 = 0; k2 < 2; ++k2) {
      bf16x8 pa0, pa1;
      {
        int pr0 = wv * 32 + l15;
        int pr1 = wv * 32 + 16 + l15;
        pa0 = *(const bf16x8*)&Ps[pr0 * 64 + (((k2 * 4 + l4) ^ (pr0 & 7)) << 3)];
        pa1 = *(const bf16x8*)&Ps[pr1 * 64 + (((k2 * 4 + l4) ^ (pr1 & 7)) << 3)];
      }
#pragma unroll
      for (int dt = 0; dt < 8; ++dt) {
        bf16x8 vf = *(const bf16x8*)&Vc[(dt * 16 + l15) * 64 + ((k2 * 32 + l4 * 8) ^ ((l15 & 7) << 3))];
        aco[0][dt] = __builtin_amdgcn_mfma_f32_16x16x32_bf16(pa0, vf, aco[0][dt], 0, 0, 0);
        aco[1][dt] = __builtin_amdgcn_mfma_f32_16x16x32_bf16(pa1, vf, aco[1][dt], 0, 0, 0);
      }
    }
    __builtin_amdgcn_s_setprio(0);

    __syncthreads();   // barrier B: all waves done reading V(kt)
    if (kt + 1 < S_ / 64) {
      STAGE_V(kt + 1);  // safe to overwrite V now; drains at next barrier A
    }
  }
#undef STAGE_V

  // final cross-lane row-sum reduce (once), then scale + write out
#pragma unroll
  for (int rg = 0; rg < 2; ++rg)
#pragma unroll
    for (int r = 0; r < 4; ++r) {
      float s = lp[rg][r];
      s += __shfl_xor(s, 1);
      s += __shfl_xor(s, 2);
      s += __shfl_xor(s, 4);
      s += __shfl_xor(s, 8);
      lp[rg][r] = 1.0f / s;
    }
#pragma unroll
  for (int rg = 0; rg < 2; ++rg)
#pragma unroll
    for (int dt = 0; dt < 8; ++dt)
#pragma unroll
      for (int r = 0; r < 4; ++r) {
        int srow = s0 + wv * 32 + rg * 16 + l4 * 4 + r;
        int col = head * HD_ + dt * 16 + l15;
        Ob[((size_t)(b * S_ + srow)) * H_ + col] = f2bf(aco[rg][dt][r] * lp[rg][r]);
      }
}

extern "C" void kernel_launch(void* const* d_in, const int* in_sizes, int n_in,
                              void* d_out, int out_size, void* d_ws, size_t ws_size,
                              hipStream_t stream)
{
  const float* X    = (const float*)d_in[0];
  const float* Wq   = (const float*)d_in[2];
  const float* bq   = (const float*)d_in[3];
  const float* Wk   = (const float*)d_in[4];
  const float* bk   = (const float*)d_in[5];
  const float* Wv   = (const float*)d_in[6];
  const float* bv   = (const float*)d_in[7];
  const float* Wo   = (const float*)d_in[8];
  const float* bo   = (const float*)d_in[9];
  float* out = (float*)d_out;

  char* ws = (char*)d_ws;
  u16* Xb    = (u16*)(ws + 0);                       // 16 MiB  X bf16 (4096 x 2048)
  u16* QKV   = (u16*)(ws + (16u << 20));             // 24 MiB  QKV bf16 (4096 x 3072)
  u16* Vt    = (u16*)(ws + (40u << 20));             //  4 MiB  V^T bf16 (B,G,HD,S)
  u16* Ab    = (u16*)(ws + (44u << 20));             // 16 MiB  attn out bf16 (4096 x 2048)
  u16* Wqkvt = (u16*)(ws + (60u << 20));             // 12 MiB  (3072 x 2048)
  u16* Wot   = (u16*)(ws + (72u << 20));             //  8 MiB  -> total 80 MiB

  const u16* Qb = QKV;            // cols 0..2047   (stride QKVW)
  const u16* Kb = QKV + 2048;     // cols 2048..2559

  // fused prelude: X cast + all weight transpose-casts in one launch
  prelude_kernel<<<dim3(14336), 256, 0, stream>>>(X, Xb, Wq, Wk, Wv, Wo, Wqkvt, Wot);

  // fused QKV projection (bias select + Q pre-scale*log2e; V written directly to Vt)
  gemm_bt<3><<<dim3(32, 24), 512, 0, stream>>>(Xb, Wqkvt, bq, bk, bv, QKV, Vt, QKVW, 2048);

  attn_kernel<<<dim3(8, 16, 2), 512, 0, stream>>>(Qb, Kb, Vt, Ab);

  // output projection (fp32 out + bias)
  gemm_bt<1><<<dim3(32, 16), 512, 0, stream>>>(Ab, Wot, bo, nullptr, nullptr, out, nullptr, 2048, 2048);
}

// Round 19
// 244.894 us; speedup vs baseline: 1.3882x; 1.3882x over previous
//
#include <hip/hip_runtime.h>
#include <cstdint>

typedef unsigned short u16;
typedef __attribute__((ext_vector_type(8))) short bf16x8;
typedef __attribute__((ext_vector_type(4))) float f32x4;

#define B_    2
#define S_    2048
#define H_    2048
#define G_    4
#define HD_   128
#define QKVW  3072   // fused QKV row width

// v_exp_f32: D = 2^S0  (exp2 semantics, ISA §3)
#define EXP2F(x) __builtin_amdgcn_exp2f(x)

__device__ __forceinline__ u16 f2bf(float f) {
  union { float f; unsigned u; } v; v.f = f;
  unsigned r = v.u + 0x7fffu + ((v.u >> 16) & 1u);
  return (u16)(r >> 16);
}

__device__ __forceinline__ void async16(void* lds_dst, const void* gsrc) {
  __builtin_amdgcn_global_load_lds(
      (__attribute__((address_space(1))) void*)gsrc,
      (__attribute__((address_space(3))) void*)lds_dst, 16, 0, 0);
}

// ------------- fused prelude: X cast (blocks 0..4095) + weight transpose-casts
// (blocks 4096..14335) in one launch -------------
__global__ __launch_bounds__(256)
void prelude_kernel(const float* __restrict__ X, u16* __restrict__ Xb,
                    const float* __restrict__ Wq, const float* __restrict__ Wk,
                    const float* __restrict__ Wv, const float* __restrict__ Wo,
                    u16* __restrict__ Wqkvt, u16* __restrict__ Wot)
{
  int id = blockIdx.x;
  if (id < 4096) {               // ---- X fp32 -> bf16, 8 elems/thread ----
    int i = id * 256 + threadIdx.x;
    const float4* p = (const float4*)X + (size_t)i * 2;
    float4 a = p[0], b = p[1];
    u16 h[8] = { f2bf(a.x), f2bf(a.y), f2bf(a.z), f2bf(a.w),
                 f2bf(b.x), f2bf(b.y), f2bf(b.z), f2bf(b.w) };
    *(uint4*)(Xb + (size_t)i * 8) = *(const uint4*)h;
    return;
  }
  id -= 4096;                    // ---- weight transpose-cast ----
  const float* W; u16* Wt; int Ndim, bx;
  if (id < 4096)      { W = Wq; Wt = Wqkvt;                        Ndim = 2048; bx = id;        }
  else if (id < 5120) { W = Wk; Wt = Wqkvt + (size_t)2048 * 2048;  Ndim = 512;  bx = id - 4096; }
  else if (id < 6144) { W = Wv; Wt = Wqkvt + (size_t)2560 * 2048;  Ndim = 512;  bx = id - 5120; }
  else                { W = Wo; Wt = Wot;                          Ndim = 2048; bx = id - 6144; }
  const int Kdim = 2048;
  const int nbx = Ndim >> 5;
  const int n0 = (bx % nbx) * 32, k0 = (bx / nbx) * 32;

  __shared__ float t[32][33];
  int tx = threadIdx.x & 31, ty = threadIdx.x >> 5;   // ty 0..7
#pragma unroll
  for (int j = 0; j < 4; ++j)
    t[ty + j * 8][tx] = W[(size_t)(k0 + ty + j * 8) * Ndim + n0 + tx];
  __syncthreads();
#pragma unroll
  for (int j = 0; j < 4; ++j)
    Wt[(size_t)(n0 + ty + j * 8) * Kdim + k0 + tx] = f2bf(t[tx][ty + j * 8]);
}

// ---------------- GEMM: C(M,N) = A(M,K) @ Bt(N,K)^T + bias ----------------
// 8 waves (512 thr), per-wave 64x32 output. R17 XCD row-strip remap.
// MODE 3 writes V columns directly to Vt (B,G,HD,S); Q pre-scaled by
// (1/sqrt(128))*log2(e) so attention uses exp2.
template <int MODE>
__global__ __launch_bounds__(512, 6)
void gemm_bt(const u16* __restrict__ A, const u16* __restrict__ Bt,
             const float* __restrict__ biasQ, const float* __restrict__ biasK,
             const float* __restrict__ biasV, void* __restrict__ Cout,
             u16* __restrict__ VtOut, int Ndim, int Kdim)
{
  __shared__ u16 As[128 * 64];
  __shared__ u16 Bs[128 * 64];
  const int tid  = threadIdx.x;
  const int lane = tid & 63;
  const int wv   = tid >> 6;            // 0..7

  // XCD remap: xcd = wgid&7 owns rows [xcd*4, xcd*4+4) x all cols.
  const int wgid = blockIdx.x + gridDim.x * blockIdx.y;
  const int xcd  = wgid & 7;
  const int idx  = wgid >> 3;
  const int row0 = (xcd * 4 + (idx & 3)) * 128;   // gridDim.x == 32
  const int col0 = (idx >> 2) * 128;

  const int wm = (wv >> 2) * 64;        // 2 row-groups
  const int wn = (wv & 3) * 32;         // 4 col-groups
  const int l15 = lane & 15, l4 = lane >> 4;

  f32x4 acc[4][2] = {};

  for (int kt = 0; kt < Kdim; kt += 64) {
    __syncthreads();
#pragma unroll
    for (int i = 0; i < 2; ++i) {
      int u = i * 512 + tid;
      int r = u >> 3, ci = u & 7;
      async16((char*)As + (i * 512 + wv * 64) * 16,
              A + (size_t)(row0 + r) * Kdim + kt + ci * 8);
    }
#pragma unroll
    for (int i = 0; i < 2; ++i) {
      int u = i * 512 + tid;
      int r = u >> 3, ci = u & 7;
      async16((char*)Bs + (i * 512 + wv * 64) * 16,
              Bt + (size_t)(col0 + r) * Kdim + kt + ci * 8);
    }
    __syncthreads();
#pragma unroll
    for (int ks = 0; ks < 2; ++ks) {
      bf16x8 af[4], bfr[2];
#pragma unroll
      for (int mt = 0; mt < 4; ++mt)
        af[mt] = *(const bf16x8*)&As[(wm + mt * 16 + l15) * 64 + ks * 32 + l4 * 8];
#pragma unroll
      for (int nt = 0; nt < 2; ++nt)
        bfr[nt] = *(const bf16x8*)&Bs[(wn + nt * 16 + l15) * 64 + ks * 32 + l4 * 8];
#pragma unroll
      for (int mt = 0; mt < 4; ++mt)
#pragma unroll
        for (int nt = 0; nt < 2; ++nt)
          acc[mt][nt] = __builtin_amdgcn_mfma_f32_16x16x32_bf16(af[mt], bfr[nt], acc[mt][nt], 0, 0, 0);
    }
  }

#pragma unroll
  for (int mt = 0; mt < 4; ++mt)
#pragma unroll
    for (int nt = 0; nt < 2; ++nt)
#pragma unroll
      for (int r = 0; r < 4; ++r) {
        int rr = row0 + wm + mt * 16 + l4 * 4 + r;
        int cc = col0 + wn + nt * 16 + l15;
        float bias;
        if (MODE == 3)
          bias = cc < 2048 ? biasQ[cc] : (cc < 2560 ? biasK[cc - 2048] : biasV[cc - 2560]);
        else
          bias = biasQ[cc];
        float v = acc[mt][nt][r] + bias;
        if (MODE == 1) {
          ((float*)Cout)[(size_t)rr * Ndim + cc] = v;
        } else {
          if (cc < 2048) v *= 0.12751743383412927f;   // (1/sqrt(128))*log2(e)
          if (cc < 2560) {
            ((u16*)Cout)[(size_t)rr * Ndim + cc] = f2bf(v);
          } else {
            int vc = cc - 2560;                 // 0..511
            int gg = vc >> 7, d = vc & 127;
            VtOut[(((size_t)((rr >> 11) * G_ + gg)) * HD_ + d) * S_ + (rr & 2047)] = f2bf(v);
          }
        }
      }
}

// ---------------- Flash attention (GQA) — R17 proven version (107us) ----------------
// 8 waves x 32 q-rows (512 thr), KVB=64, direct-Q, exp2 softmax.
// K double-buffered in LDS (DMA-staged: linear writes, b128 reads — R18's
// K-direct-from-global scattered each wave over 16 x 6KB-stride segments
// and halved MfmaUtil; reverted). V single-buffered (barriers A/B handoff).
// LDS: Ks[2] 0/8192 (32KB) | Vs 16384 (16KB) | Ps 24576 (32KB) = 80KB.
__global__ __launch_bounds__(512, 2)
void attn_kernel(const u16* __restrict__ Qb, const u16* __restrict__ Kb,
                 const u16* __restrict__ Vt, u16* __restrict__ Ob)
{
  __shared__ u16 SH[40960];          // 80KB
  u16* Ps = SH + 24576;
  const int tid  = threadIdx.x;
  const int lane = tid & 63, wv = tid >> 6;   // wv 0..7
  const int l15 = lane & 15, l4 = lane >> 4;
  const int qt = blockIdx.x, head = blockIdx.y, b = blockIdx.z;
  const int g = head >> 2;
  const int s0 = qt * 256;

  // --- Q fragments direct from global ---
  bf16x8 qf[2][4];
  {
    const u16* qbase = Qb + ((size_t)(b * S_ + s0 + wv * 32 + l15)) * QKVW + head * HD_ + l4 * 8;
#pragma unroll
    for (int rg = 0; rg < 2; ++rg)
#pragma unroll
      for (int ks = 0; ks < 4; ++ks)
        qf[rg][ks] = *(const bf16x8*)(qbase + (size_t)rg * 16 * QKVW + ks * 32);
  }

  float m_r[2][4], lp[2][4];
#pragma unroll
  for (int rg = 0; rg < 2; ++rg)
#pragma unroll
    for (int r = 0; r < 4; ++r) { m_r[rg][r] = 0.f; lp[rg][r] = 0.f; }
  f32x4 aco[2][8] = {};

#define STAGE_K(buf, kt_)                                                      \
  _Pragma("unroll")                                                            \
  for (int i = 0; i < 2; ++i) {                                                \
    int u = i * 512 + tid;                                                     \
    int r = u >> 4;                                                            \
    int ci = (u & 15) ^ (r & 7);                                               \
    async16((char*)SH + (buf) * 16384 + (i * 512 + wv * 64) * 16,              \
            Kb + ((size_t)(b * S_ + (kt_) * 64 + r)) * QKVW + g * HD_ + ci * 8); \
  }
#define STAGE_V(kt_)                                                           \
  _Pragma("unroll")                                                            \
  for (int i = 0; i < 2; ++i) {                                                \
    int u = i * 512 + tid;                                                     \
    int r = u >> 3;                                                            \
    int ci = (u & 7) ^ (r & 7);                                                \
    async16((char*)SH + 32768 + (i * 512 + wv * 64) * 16,                      \
            Vt + (((size_t)(b * G_ + g)) * HD_ + r) * S_ + (kt_) * 64 + ci * 8); \
  }

  STAGE_K(0, 0);
  STAGE_V(0);
  __syncthreads();   // tile 0 (K0, V0) resident

  const u16* Vc = SH + 16384;
  int kcur = 0;
  for (int kt = 0; kt < S_ / 64; ++kt) {
    if (kt + 1 < S_ / 64) {    // issue next K tile early
      STAGE_K(kcur ^ 1, kt + 1);
    }
    const u16* Kc = SH + kcur * 8192;

    // QK^T (scores in log2 domain via Q pre-scale)
    f32x4 sc[2][4] = {};
    __builtin_amdgcn_s_setprio(1);
#pragma unroll
    for (int ct = 0; ct < 4; ++ct)
#pragma unroll
      for (int ks = 0; ks < 4; ++ks) {
        bf16x8 kf = *(const bf16x8*)&Kc[(ct * 16 + l15) * 128 + ((ks * 32 + l4 * 8) ^ ((l15 & 7) << 3))];
        sc[0][ct] = __builtin_amdgcn_mfma_f32_16x16x32_bf16(qf[0][ks], kf, sc[0][ct], 0, 0, 0);
        sc[1][ct] = __builtin_amdgcn_mfma_f32_16x16x32_bf16(qf[1][ks], kf, sc[1][ct], 0, 0, 0);
      }
    __builtin_amdgcn_s_setprio(0);

    // per-lane overflow/underflow check (log2 domain; P bounded by 2^8)
    float lm[2][4];
    bool resc = false;
#pragma unroll
    for (int rg = 0; rg < 2; ++rg)
#pragma unroll
      for (int r = 0; r < 4; ++r) {
        lm[rg][r] = fmaxf(fmaxf(sc[rg][0][r], sc[rg][1][r]),
                          fmaxf(sc[rg][2][r], sc[rg][3][r]));
        float d = lm[rg][r] - m_r[rg][r];
        resc |= (d > 8.0f) | (d < -60.0f);
      }
    if (__ballot(resc)) {     // rare: full per-row max update + rescale
#pragma unroll
      for (int rg = 0; rg < 2; ++rg)
#pragma unroll
        for (int r = 0; r < 4; ++r) {
          float mx = lm[rg][r];
          mx = fmaxf(mx, __shfl_xor(mx, 1));
          mx = fmaxf(mx, __shfl_xor(mx, 2));
          mx = fmaxf(mx, __shfl_xor(mx, 4));
          mx = fmaxf(mx, __shfl_xor(mx, 8));
          float mn = fmaxf(m_r[rg][r], mx);
          float al = EXP2F(m_r[rg][r] - mn);
          m_r[rg][r] = mn;
          lp[rg][r] *= al;
#pragma unroll
          for (int dt = 0; dt < 8; ++dt)
            aco[rg][dt][r] *= al;
        }
    }

    // P = exp2(s - m); per-lane partial row-sums; P rows are per-wave-private
#pragma unroll
    for (int rg = 0; rg < 2; ++rg)
#pragma unroll
      for (int ct = 0; ct < 4; ++ct)
#pragma unroll
        for (int r = 0; r < 4; ++r) {
          float p = EXP2F(sc[rg][ct][r] - m_r[rg][r]);
          lp[rg][r] += p;
          int row = wv * 32 + rg * 16 + l4 * 4 + r;
          int col = ct * 16 + l15;
          Ps[row * 64 + (((col >> 3) ^ (row & 7)) << 3) + (col & 7)] = f2bf(p);
        }

    __syncthreads();   // barrier A: V(kt) staging (issued end of prev iter) drained

    // PV: V from LDS (single-buffered; handoff via barriers A/B)
    __builtin_amdgcn_s_setprio(1);
#pragma unroll
    for (int k2 = 0; k2 < 2; ++k2) {
      bf16x8 pa0, pa1;
      {
        int pr0 = wv * 32 + l15;
        int pr1 = wv * 32 + 16 + l15;
        pa0 = *(const bf16x8*)&Ps[pr0 * 64 + (((k2 * 4 + l4) ^ (pr0 & 7)) << 3)];
        pa1 = *(const bf16x8*)&Ps[pr1 * 64 + (((k2 * 4 + l4) ^ (pr1 & 7)) << 3)];
      }
#pragma unroll
      for (int dt = 0; dt < 8; ++dt) {
        bf16x8 vf = *(const bf16x8*)&Vc[(dt * 16 + l15) * 64 + ((k2 * 32 + l4 * 8) ^ ((l15 & 7) << 3))];
        aco[0][dt] = __builtin_amdgcn_mfma_f32_16x16x32_bf16(pa0, vf, aco[0][dt], 0, 0, 0);
        aco[1][dt] = __builtin_amdgcn_mfma_f32_16x16x32_bf16(pa1, vf, aco[1][dt], 0, 0, 0);
      }
    }
    __builtin_amdgcn_s_setprio(0);

    __syncthreads();   // barrier B: all waves done reading V(kt)
    if (kt + 1 < S_ / 64) {
      STAGE_V(kt + 1);  // safe to overwrite V now; drains at next barrier A
    }
    kcur ^= 1;
  }
#undef STAGE_K
#undef STAGE_V

  // final cross-lane row-sum reduce (once), then scale + write out
#pragma unroll
  for (int rg = 0; rg < 2; ++rg)
#pragma unroll
    for (int r = 0; r < 4; ++r) {
      float s = lp[rg][r];
      s += __shfl_xor(s, 1);
      s += __shfl_xor(s, 2);
      s += __shfl_xor(s, 4);
      s += __shfl_xor(s, 8);
      lp[rg][r] = 1.0f / s;
    }
#pragma unroll
  for (int rg = 0; rg < 2; ++rg)
#pragma unroll
    for (int dt = 0; dt < 8; ++dt)
#pragma unroll
      for (int r = 0; r < 4; ++r) {
        int srow = s0 + wv * 32 + rg * 16 + l4 * 4 + r;
        int col = head * HD_ + dt * 16 + l15;
        Ob[((size_t)(b * S_ + srow)) * H_ + col] = f2bf(aco[rg][dt][r] * lp[rg][r]);
      }
}

extern "C" void kernel_launch(void* const* d_in, const int* in_sizes, int n_in,
                              void* d_out, int out_size, void* d_ws, size_t ws_size,
                              hipStream_t stream)
{
  const float* X    = (const float*)d_in[0];
  const float* Wq   = (const float*)d_in[2];
  const float* bq   = (const float*)d_in[3];
  const float* Wk   = (const float*)d_in[4];
  const float* bk   = (const float*)d_in[5];
  const float* Wv   = (const float*)d_in[6];
  const float* bv   = (const float*)d_in[7];
  const float* Wo   = (const float*)d_in[8];
  const float* bo   = (const float*)d_in[9];
  float* out = (float*)d_out;

  char* ws = (char*)d_ws;
  u16* Xb    = (u16*)(ws + 0);                       // 16 MiB  X bf16 (4096 x 2048)
  u16* QKV   = (u16*)(ws + (16u << 20));             // 24 MiB  QKV bf16 (4096 x 3072)
  u16* Vt    = (u16*)(ws + (40u << 20));             //  4 MiB  V^T bf16 (B,G,HD,S)
  u16* Ab    = (u16*)(ws + (44u << 20));             // 16 MiB  attn out bf16 (4096 x 2048)
  u16* Wqkvt = (u16*)(ws + (60u << 20));             // 12 MiB  (3072 x 2048)
  u16* Wot   = (u16*)(ws + (72u << 20));             //  8 MiB  -> total 80 MiB

  const u16* Qb = QKV;            // cols 0..2047   (stride QKVW)
  const u16* Kb = QKV + 2048;     // cols 2048..2559

  // fused prelude: X cast + all weight transpose-casts in one launch
  prelude_kernel<<<dim3(14336), 256, 0, stream>>>(X, Xb, Wq, Wk, Wv, Wo, Wqkvt, Wot);

  // fused QKV projection (bias select + Q pre-scale*log2e; V written directly to Vt)
  gemm_bt<3><<<dim3(32, 24), 512, 0, stream>>>(Xb, Wqkvt, bq, bk, bv, QKV, Vt, QKVW, 2048);

  attn_kernel<<<dim3(8, 16, 2), 512, 0, stream>>>(Qb, Kb, Vt, Ab);

  // output projection (fp32 out + bias)
  gemm_bt<1><<<dim3(32, 16), 512, 0, stream>>>(Ab, Wot, bo, nullptr, nullptr, out, nullptr, 2048, 2048);
}

// Round 21
// 241.498 us; speedup vs baseline: 1.4077x; 1.0141x over previous
//
#include <hip/hip_runtime.h>
#include <cstdint>

typedef unsigned short u16;
typedef __attribute__((ext_vector_type(8))) short bf16x8;
typedef __attribute__((ext_vector_type(4))) float f32x4;

#define B_    2
#define S_    2048
#define H_    2048
#define G_    4
#define HD_   128
#define QKVW  3072   // fused QKV row width

// v_exp_f32: D = 2^S0  (exp2 semantics, ISA §3)
#define EXP2F(x) __builtin_amdgcn_exp2f(x)

__device__ __forceinline__ u16 f2bf(float f) {
  union { float f; unsigned u; } v; v.f = f;
  unsigned r = v.u + 0x7fffu + ((v.u >> 16) & 1u);
  return (u16)(r >> 16);
}

__device__ __forceinline__ void async16(void* lds_dst, const void* gsrc) {
  __builtin_amdgcn_global_load_lds(
      (__attribute__((address_space(1))) void*)gsrc,
      (__attribute__((address_space(3))) void*)lds_dst, 16, 0, 0);
}

// ------------- fused prelude: X cast (blocks 0..4095) + weight transpose-casts
// (blocks 4096..14335) in one launch -------------
__global__ __launch_bounds__(256)
void prelude_kernel(const float* __restrict__ X, u16* __restrict__ Xb,
                    const float* __restrict__ Wq, const float* __restrict__ Wk,
                    const float* __restrict__ Wv, const float* __restrict__ Wo,
                    u16* __restrict__ Wqkvt, u16* __restrict__ Wot)
{
  int id = blockIdx.x;
  if (id < 4096) {               // ---- X fp32 -> bf16, 8 elems/thread ----
    int i = id * 256 + threadIdx.x;
    const float4* p = (const float4*)X + (size_t)i * 2;
    float4 a = p[0], b = p[1];
    u16 h[8] = { f2bf(a.x), f2bf(a.y), f2bf(a.z), f2bf(a.w),
                 f2bf(b.x), f2bf(b.y), f2bf(b.z), f2bf(b.w) };
    *(uint4*)(Xb + (size_t)i * 8) = *(const uint4*)h;
    return;
  }
  id -= 4096;                    // ---- weight transpose-cast ----
  const float* W; u16* Wt; int Ndim, bx;
  if (id < 4096)      { W = Wq; Wt = Wqkvt;                        Ndim = 2048; bx = id;        }
  else if (id < 5120) { W = Wk; Wt = Wqkvt + (size_t)2048 * 2048;  Ndim = 512;  bx = id - 4096; }
  else if (id < 6144) { W = Wv; Wt = Wqkvt + (size_t)2560 * 2048;  Ndim = 512;  bx = id - 5120; }
  else                { W = Wo; Wt = Wot;                          Ndim = 2048; bx = id - 6144; }
  const int Kdim = 2048;
  const int nbx = Ndim >> 5;
  const int n0 = (bx % nbx) * 32, k0 = (bx / nbx) * 32;

  __shared__ float t[32][33];
  int tx = threadIdx.x & 31, ty = threadIdx.x >> 5;   // ty 0..7
#pragma unroll
  for (int j = 0; j < 4; ++j)
    t[ty + j * 8][tx] = W[(size_t)(k0 + ty + j * 8) * Ndim + n0 + tx];
  __syncthreads();
#pragma unroll
  for (int j = 0; j < 4; ++j)
    Wt[(size_t)(n0 + ty + j * 8) * Kdim + k0 + tx] = f2bf(t[tx][ty + j * 8]);
}

// ---------------- GEMM: C(M,N) = A(M,K) @ Bt(N,K)^T + bias ----------------
// 8 waves (512 thr), per-wave 64x32 output. R17 XCD row-strip remap.
// MODE 3 writes V columns directly to Vt (B,G,HD,S); Q pre-scaled by
// (1/sqrt(128))*log2(e) so attention uses exp2.
template <int MODE>
__global__ __launch_bounds__(512, 6)
void gemm_bt(const u16* __restrict__ A, const u16* __restrict__ Bt,
             const float* __restrict__ biasQ, const float* __restrict__ biasK,
             const float* __restrict__ biasV, void* __restrict__ Cout,
             u16* __restrict__ VtOut, int Ndim, int Kdim)
{
  __shared__ u16 As[128 * 64];
  __shared__ u16 Bs[128 * 64];
  const int tid  = threadIdx.x;
  const int lane = tid & 63;
  const int wv   = tid >> 6;            // 0..7

  // XCD remap: xcd = wgid&7 owns rows [xcd*4, xcd*4+4) x all cols.
  const int wgid = blockIdx.x + gridDim.x * blockIdx.y;
  const int xcd  = wgid & 7;
  const int idx  = wgid >> 3;
  const int row0 = (xcd * 4 + (idx & 3)) * 128;   // gridDim.x == 32
  const int col0 = (idx >> 2) * 128;

  const int wm = (wv >> 2) * 64;        // 2 row-groups
  const int wn = (wv & 3) * 32;         // 4 col-groups
  const int l15 = lane & 15, l4 = lane >> 4;

  f32x4 acc[4][2] = {};

  for (int kt = 0; kt < Kdim; kt += 64) {
    __syncthreads();
#pragma unroll
    for (int i = 0; i < 2; ++i) {
      int u = i * 512 + tid;
      int r = u >> 3, ci = u & 7;
      async16((char*)As + (i * 512 + wv * 64) * 16,
              A + (size_t)(row0 + r) * Kdim + kt + ci * 8);
    }
#pragma unroll
    for (int i = 0; i < 2; ++i) {
      int u = i * 512 + tid;
      int r = u >> 3, ci = u & 7;
      async16((char*)Bs + (i * 512 + wv * 64) * 16,
              Bt + (size_t)(col0 + r) * Kdim + kt + ci * 8);
    }
    __syncthreads();
#pragma unroll
    for (int ks = 0; ks < 2; ++ks) {
      bf16x8 af[4], bfr[2];
#pragma unroll
      for (int mt = 0; mt < 4; ++mt)
        af[mt] = *(const bf16x8*)&As[(wm + mt * 16 + l15) * 64 + ks * 32 + l4 * 8];
#pragma unroll
      for (int nt = 0; nt < 2; ++nt)
        bfr[nt] = *(const bf16x8*)&Bs[(wn + nt * 16 + l15) * 64 + ks * 32 + l4 * 8];
#pragma unroll
      for (int mt = 0; mt < 4; ++mt)
#pragma unroll
        for (int nt = 0; nt < 2; ++nt)
          acc[mt][nt] = __builtin_amdgcn_mfma_f32_16x16x32_bf16(af[mt], bfr[nt], acc[mt][nt], 0, 0, 0);
    }
  }

#pragma unroll
  for (int mt = 0; mt < 4; ++mt)
#pragma unroll
    for (int nt = 0; nt < 2; ++nt)
#pragma unroll
      for (int r = 0; r < 4; ++r) {
        int rr = row0 + wm + mt * 16 + l4 * 4 + r;
        int cc = col0 + wn + nt * 16 + l15;
        float bias;
        if (MODE == 3)
          bias = cc < 2048 ? biasQ[cc] : (cc < 2560 ? biasK[cc - 2048] : biasV[cc - 2560]);
        else
          bias = biasQ[cc];
        float v = acc[mt][nt][r] + bias;
        if (MODE == 1) {
          ((float*)Cout)[(size_t)rr * Ndim + cc] = v;
        } else {
          if (cc < 2048) v *= 0.12751743383412927f;   // (1/sqrt(128))*log2(e)
          if (cc < 2560) {
            ((u16*)Cout)[(size_t)rr * Ndim + cc] = f2bf(v);
          } else {
            int vc = cc - 2560;                 // 0..511
            int gg = vc >> 7, d = vc & 127;
            VtOut[(((size_t)((rr >> 11) * G_ + gg)) * HD_ + d) * S_ + (rr & 2047)] = f2bf(v);
          }
        }
      }
}

// ---------------- Flash attention (GQA) ----------------
// 8 waves x 32 q-rows (512 thr), KVB=64, direct-Q, exp2 softmax.
// R21 = R20 schedule (ONE barrier per tile; V triple-buffered, K double-
// buffered) with the V-read pointer fixed: each V buffer is 8192 u16, read
// offset is vcur*8192 u16 (R20 used vcur*4096 — bytes/u16 confusion, read
// half-overlapping buffers, deterministic absmax 0.15).
// Handoff ledger (verified): K(t+1) write after barrier(t-1) > QK^T(t-1)
// read of same buf; V(t+1) write after barrier(t-1) > PV(t-2) read of same
// slot; every read drained one barrier earlier.
// LDS u16 layout: Ks[2] 0/8192 | Vs[3] 16384/24576/32768 | Ps 40960..57343.
__global__ __launch_bounds__(512, 2)
void attn_kernel(const u16* __restrict__ Qb, const u16* __restrict__ Kb,
                 const u16* __restrict__ Vt, u16* __restrict__ Ob)
{
  __shared__ u16 SH[57344];          // 112KB
  u16* Ps = SH + 40960;
  const int tid  = threadIdx.x;
  const int lane = tid & 63, wv = tid >> 6;   // wv 0..7
  const int l15 = lane & 15, l4 = lane >> 4;
  const int qt = blockIdx.x, head = blockIdx.y, b = blockIdx.z;
  const int g = head >> 2;
  const int s0 = qt * 256;

  // --- Q fragments direct from global ---
  bf16x8 qf[2][4];
  {
    const u16* qbase = Qb + ((size_t)(b * S_ + s0 + wv * 32 + l15)) * QKVW + head * HD_ + l4 * 8;
#pragma unroll
    for (int rg = 0; rg < 2; ++rg)
#pragma unroll
      for (int ks = 0; ks < 4; ++ks)
        qf[rg][ks] = *(const bf16x8*)(qbase + (size_t)rg * 16 * QKVW + ks * 32);
  }

  float m_r[2][4], lp[2][4];
#pragma unroll
  for (int rg = 0; rg < 2; ++rg)
#pragma unroll
    for (int r = 0; r < 4; ++r) { m_r[rg][r] = 0.f; lp[rg][r] = 0.f; }
  f32x4 aco[2][8] = {};

#define STAGE_K(buf, kt_)                                                      \
  _Pragma("unroll")                                                            \
  for (int i = 0; i < 2; ++i) {                                                \
    int u = i * 512 + tid;                                                     \
    int r = u >> 4;                                                            \
    int ci = (u & 15) ^ (r & 7);                                               \
    async16((char*)SH + (buf) * 16384 + (i * 512 + wv * 64) * 16,              \
            Kb + ((size_t)(b * S_ + (kt_) * 64 + r)) * QKVW + g * HD_ + ci * 8); \
  }
#define STAGE_V(buf, kt_)                                                      \
  _Pragma("unroll")                                                            \
  for (int i = 0; i < 2; ++i) {                                                \
    int u = i * 512 + tid;                                                     \
    int r = u >> 3;                                                            \
    int ci = (u & 7) ^ (r & 7);                                                \
    async16((char*)SH + 32768 + (buf) * 16384 + (i * 512 + wv * 64) * 16,      \
            Vt + (((size_t)(b * G_ + g)) * HD_ + r) * S_ + (kt_) * 64 + ci * 8); \
  }

  STAGE_K(0, 0);
  STAGE_V(0, 0);
  __syncthreads();   // tile 0 (K0, V0) resident

  int vn = 1;        // v-buffer index for tile kt+1 (rotates 0,1,2)
  for (int kt = 0; kt < S_ / 64; ++kt) {
    if (kt + 1 < S_ / 64) {    // issue next tile early; drained at this iter's barrier
      STAGE_K((kt + 1) & 1, kt + 1);
      STAGE_V(vn, kt + 1);
    }
    const u16* Kc = SH + (kt & 1) * 8192;
    // V(kt)'s slot: previous vn; each V buffer is 8192 u16 (16KB)
    const int vcur = (vn + 2) % 3;
    const u16* Vc = SH + 16384 + vcur * 8192;

    // QK^T (scores in log2 domain via Q pre-scale)
    f32x4 sc[2][4] = {};
    __builtin_amdgcn_s_setprio(1);
#pragma unroll
    for (int ct = 0; ct < 4; ++ct)
#pragma unroll
      for (int ks = 0; ks < 4; ++ks) {
        bf16x8 kf = *(const bf16x8*)&Kc[(ct * 16 + l15) * 128 + ((ks * 32 + l4 * 8) ^ ((l15 & 7) << 3))];
        sc[0][ct] = __builtin_amdgcn_mfma_f32_16x16x32_bf16(qf[0][ks], kf, sc[0][ct], 0, 0, 0);
        sc[1][ct] = __builtin_amdgcn_mfma_f32_16x16x32_bf16(qf[1][ks], kf, sc[1][ct], 0, 0, 0);
      }
    __builtin_amdgcn_s_setprio(0);

    // per-lane overflow/underflow check (log2 domain; P bounded by 2^8)
    float lm[2][4];
    bool resc = false;
#pragma unroll
    for (int rg = 0; rg < 2; ++rg)
#pragma unroll
      for (int r = 0; r < 4; ++r) {
        lm[rg][r] = fmaxf(fmaxf(sc[rg][0][r], sc[rg][1][r]),
                          fmaxf(sc[rg][2][r], sc[rg][3][r]));
        float d = lm[rg][r] - m_r[rg][r];
        resc |= (d > 8.0f) | (d < -60.0f);
      }
    if (__ballot(resc)) {     // rare: full per-row max update + rescale
#pragma unroll
      for (int rg = 0; rg < 2; ++rg)
#pragma unroll
        for (int r = 0; r < 4; ++r) {
          float mx = lm[rg][r];
          mx = fmaxf(mx, __shfl_xor(mx, 1));
          mx = fmaxf(mx, __shfl_xor(mx, 2));
          mx = fmaxf(mx, __shfl_xor(mx, 4));
          mx = fmaxf(mx, __shfl_xor(mx, 8));
          float mn = fmaxf(m_r[rg][r], mx);
          float al = EXP2F(m_r[rg][r] - mn);
          m_r[rg][r] = mn;
          lp[rg][r] *= al;
#pragma unroll
          for (int dt = 0; dt < 8; ++dt)
            aco[rg][dt][r] *= al;
        }
    }

    // P = exp2(s - m); per-lane partial row-sums; P rows are per-wave-private
#pragma unroll
    for (int rg = 0; rg < 2; ++rg)
#pragma unroll
      for (int ct = 0; ct < 4; ++ct)
#pragma unroll
        for (int r = 0; r < 4; ++r) {
          float p = EXP2F(sc[rg][ct][r] - m_r[rg][r]);
          lp[rg][r] += p;
          int row = wv * 32 + rg * 16 + l4 * 4 + r;
          int col = ct * 16 + l15;
          Ps[row * 64 + (((col >> 3) ^ (row & 7)) << 3) + (col & 7)] = f2bf(p);
        }

    __syncthreads();   // SINGLE barrier: drains K/V(kt+1) stages; orders all handoffs

    // PV: V(kt) from LDS (drained at barrier(kt-1))
    __builtin_amdgcn_s_setprio(1);
#pragma unroll
    for (int k2 = 0; k2 < 2; ++k2) {
      bf16x8 pa0, pa1;
      {
        int pr0 = wv * 32 + l15;
        int pr1 = wv * 32 + 16 + l15;
        pa0 = *(const bf16x8*)&Ps[pr0 * 64 + (((k2 * 4 + l4) ^ (pr0 & 7)) << 3)];
        pa1 = *(const bf16x8*)&Ps[pr1 * 64 + (((k2 * 4 + l4) ^ (pr1 & 7)) << 3)];
      }
#pragma unroll
      for (int dt = 0; dt < 8; ++dt) {
        bf16x8 vf = *(const bf16x8*)&Vc[(dt * 16 + l15) * 64 + ((k2 * 32 + l4 * 8) ^ ((l15 & 7) << 3))];
        aco[0][dt] = __builtin_amdgcn_mfma_f32_16x16x32_bf16(pa0, vf, aco[0][dt], 0, 0, 0);
        aco[1][dt] = __builtin_amdgcn_mfma_f32_16x16x32_bf16(pa1, vf, aco[1][dt], 0, 0, 0);
      }
    }
    __builtin_amdgcn_s_setprio(0);

    vn = (vn == 2) ? 0 : vn + 1;
  }
#undef STAGE_K
#undef STAGE_V

  // final cross-lane row-sum reduce (once), then scale + write out
#pragma unroll
  for (int rg = 0; rg < 2; ++rg)
#pragma unroll
    for (int r = 0; r < 4; ++r) {
      float s = lp[rg][r];
      s += __shfl_xor(s, 1);
      s += __shfl_xor(s, 2);
      s += __shfl_xor(s, 4);
      s += __shfl_xor(s, 8);
      lp[rg][r] = 1.0f / s;
    }
#pragma unroll
  for (int rg = 0; rg < 2; ++rg)
#pragma unroll
    for (int dt = 0; dt < 8; ++dt)
#pragma unroll
      for (int r = 0; r < 4; ++r) {
        int srow = s0 + wv * 32 + rg * 16 + l4 * 4 + r;
        int col = head * HD_ + dt * 16 + l15;
        Ob[((size_t)(b * S_ + srow)) * H_ + col] = f2bf(aco[rg][dt][r] * lp[rg][r]);
      }
}

extern "C" void kernel_launch(void* const* d_in, const int* in_sizes, int n_in,
                              void* d_out, int out_size, void* d_ws, size_t ws_size,
                              hipStream_t stream)
{
  const float* X    = (const float*)d_in[0];
  const float* Wq   = (const float*)d_in[2];
  const float* bq   = (const float*)d_in[3];
  const float* Wk   = (const float*)d_in[4];
  const float* bk   = (const float*)d_in[5];
  const float* Wv   = (const float*)d_in[6];
  const float* bv   = (const float*)d_in[7];
  const float* Wo   = (const float*)d_in[8];
  const float* bo   = (const float*)d_in[9];
  float* out = (float*)d_out;

  char* ws = (char*)d_ws;
  u16* Xb    = (u16*)(ws + 0);                       // 16 MiB  X bf16 (4096 x 2048)
  u16* QKV   = (u16*)(ws + (16u << 20));             // 24 MiB  QKV bf16 (4096 x 3072)
  u16* Vt    = (u16*)(ws + (40u << 20));             //  4 MiB  V^T bf16 (B,G,HD,S)
  u16* Ab    = (u16*)(ws + (44u << 20));             // 16 MiB  attn out bf16 (4096 x 2048)
  u16* Wqkvt = (u16*)(ws + (60u << 20));             // 12 MiB  (3072 x 2048)
  u16* Wot   = (u16*)(ws + (72u << 20));             //  8 MiB  -> total 80 MiB

  const u16* Qb = QKV;            // cols 0..2047   (stride QKVW)
  const u16* Kb = QKV + 2048;     // cols 2048..2559

  // fused prelude: X cast + all weight transpose-casts in one launch
  prelude_kernel<<<dim3(14336), 256, 0, stream>>>(X, Xb, Wq, Wk, Wv, Wo, Wqkvt, Wot);

  // fused QKV projection (bias select + Q pre-scale*log2e; V written directly to Vt)
  gemm_bt<3><<<dim3(32, 24), 512, 0, stream>>>(Xb, Wqkvt, bq, bk, bv, QKV, Vt, QKVW, 2048);

  attn_kernel<<<dim3(8, 16, 2), 512, 0, stream>>>(Qb, Kb, Vt, Ab);

  // output projection (fp32 out + bias)
  gemm_bt<1><<<dim3(32, 16), 512, 0, stream>>>(Ab, Wot, bo, nullptr, nullptr, out, nullptr, 2048, 2048);
}